// Round 14
// baseline (237.454 us; speedup 1.0000x reference)
//
#include <hip/hip_runtime.h>
#include <math.h>

#define BB 16
#define SS 256
#define FF 512
#define EE 128
#define HH 64
#define GG 192  // 3H
#define LL 8
#define TT 16   // scan tile count (SS/16)

__device__ __forceinline__ float sigmoid_f(float x) {
    return 1.0f / (1.0f + __expf(-x));
}
__device__ __forceinline__ float tanh_f(float x) {
    return 1.0f - 2.0f / (1.0f + __expf(2.0f * x));
}

// ---------------------------------------------------------------------------
// Generic C[m,n] = sum_k A[m,k] * Bm[n,k] + bias[n]
// ---------------------------------------------------------------------------
__device__ __forceinline__ void gemm_bt_body(
    const float* __restrict__ A, const float* __restrict__ Bm,
    const float* __restrict__ bias, float* __restrict__ C,
    int N, int K)
{
    __shared__ float As[32][68];
    __shared__ float Bs[64][68];
    const int t = threadIdx.x;
    const int row0 = blockIdx.x * 32;
    const int col0 = blockIdx.y * 64;
    const int tr = t & 7;
    const int tc = t >> 3;
    float acc[4][2] = {{0.f,0.f},{0.f,0.f},{0.f,0.f},{0.f,0.f}};

    for (int k0 = 0; k0 < K; k0 += 64) {
        {
            int r = t >> 3;
            int q = t & 7;
            const float* src = &A[(size_t)(row0 + r) * K + k0];
            #pragma unroll
            for (int it = 0; it < 2; ++it) {
                int kk = (q + it * 8) * 4;
                *(float4*)&As[r][kk] = *(const float4*)&src[kk];
            }
        }
        {
            int r = t >> 2;
            int q = t & 3;
            int n = col0 + r;
            #pragma unroll
            for (int it = 0; it < 4; ++it) {
                int kk = (q + it * 4) * 4;
                float4 v = {0.f, 0.f, 0.f, 0.f};
                if (n < N) v = *(const float4*)&Bm[(size_t)n * K + k0 + kk];
                *(float4*)&Bs[r][kk] = v;
            }
        }
        __syncthreads();
        #pragma unroll
        for (int k = 0; k < 64; k += 4) {
            float4 av[4], bv[2];
            #pragma unroll
            for (int i = 0; i < 4; ++i) av[i] = *(const float4*)&As[tr + 8*i][k];
            #pragma unroll
            for (int j = 0; j < 2; ++j) bv[j] = *(const float4*)&Bs[tc + 32*j][k];
            #pragma unroll
            for (int i = 0; i < 4; ++i)
                #pragma unroll
                for (int j = 0; j < 2; ++j)
                    acc[i][j] += av[i].x*bv[j].x + av[i].y*bv[j].y
                               + av[i].z*bv[j].z + av[i].w*bv[j].w;
        }
        __syncthreads();
    }

    #pragma unroll
    for (int i = 0; i < 4; ++i) {
        int r = row0 + tr + 8*i;
        #pragma unroll
        for (int j = 0; j < 2; ++j) {
            int c = col0 + tc + 32*j;
            if (c < N) C[(size_t)r * N + c] = acc[i][j] + bias[c];
        }
    }
}

__global__ __launch_bounds__(256) void gemm_bt(
    const float* __restrict__ A, const float* __restrict__ Bm,
    const float* __restrict__ bias, float* __restrict__ C,
    int N, int K)
{
    gemm_bt_body(A, Bm, bias, C, N, K);
}

__global__ __launch_bounds__(256) void gemm_bt_dual(
    const float* __restrict__ A,
    const float* __restrict__ B0, const float* __restrict__ bias0, float* __restrict__ C0,
    const float* __restrict__ B1, const float* __restrict__ bias1, float* __restrict__ C1,
    int N, int K)
{
    const float* Bm   = blockIdx.z ? B1    : B0;
    const float* bias = blockIdx.z ? bias1 : bias0;
    float*       C    = blockIdx.z ? C1    : C0;
    gemm_bt_body(A, Bm, bias, C, N, K);
}

// ---------------------------------------------------------------------------
// GRU scan (r14). r10 structure (3 waves/chain, one gate per wave, lgkm-only
// barrier, double-buffered gh). WEIGHTS PARKED IN AGPRs: the accumulator
// file is the one register tier not yet tried. v_accvgpr_write/read via
// `asm volatile` is opaque to every mechanism that defeated r2-r12:
//   - cannot be rematerialized (asm has unknown side effects)
//   - cannot be hoisted/CSE'd out of the loop (volatile)
//   - no array alloca for SROA to fumble (64 named scalars)
// Per step each chunk re-reads its 4 weights from AGPRs (~2-4 cyc in-file,
// no memory pipe) instead of L1/L2 (~400 cyc/step exposed in r10/r11).
// Arch demand ~56 VGPR + 64 AGPR = 120 regs, fits any budget.
// ---------------------------------------------------------------------------
__global__ __launch_bounds__(192, 1)
__attribute__((amdgpu_waves_per_eu(1, 1)))
void gru_kernel(
    const float* __restrict__ xpa, const float* __restrict__ xpb,
    const float* __restrict__ Whh_a, const float* __restrict__ bhh_a,
    const float* __restrict__ Whh_b, const float* __restrict__ bhh_b,
    float* __restrict__ hs_a, float* __restrict__ hs_b)
{
    const int blk = blockIdx.x;
    const int b = blk >> 1;
    const int which = blk & 1;
    const float* xp  = which ? xpb   : xpa;
    const float* Whh = which ? Whh_b : Whh_a;
    const float* bhh = which ? bhh_b : bhh_a;
    float* hs        = which ? hs_b  : hs_a;

    const int t = threadIdx.x;       // 0..191
    const int g = t >> 6;            // gate: 0=r, 1=z, 2=n
    const int j = t & 63;

    __shared__ float gh_s[2][GG];

    const float4* wrow = (const float4*)&Whh[(size_t)(g * 64 + j) * HH];

    // 64 named AGPR-resident weight scalars.
#define AWDECL(i) float aw##i##0, aw##i##1, aw##i##2, aw##i##3
    AWDECL(0);  AWDECL(1);  AWDECL(2);  AWDECL(3);
    AWDECL(4);  AWDECL(5);  AWDECL(6);  AWDECL(7);
    AWDECL(8);  AWDECL(9);  AWDECL(10); AWDECL(11);
    AWDECL(12); AWDECL(13); AWDECL(14); AWDECL(15);
#undef AWDECL
#define AWSET(i)                                                               \
    {                                                                          \
        float4 v = wrow[i];                                                    \
        asm volatile("v_accvgpr_write_b32 %0, %1" : "=a"(aw##i##0) : "v"(v.x));\
        asm volatile("v_accvgpr_write_b32 %0, %1" : "=a"(aw##i##1) : "v"(v.y));\
        asm volatile("v_accvgpr_write_b32 %0, %1" : "=a"(aw##i##2) : "v"(v.z));\
        asm volatile("v_accvgpr_write_b32 %0, %1" : "=a"(aw##i##3) : "v"(v.w));\
    }
    AWSET(0)  AWSET(1)  AWSET(2)  AWSET(3)
    AWSET(4)  AWSET(5)  AWSET(6)  AWSET(7)
    AWSET(8)  AWSET(9)  AWSET(10) AWSET(11)
    AWSET(12) AWSET(13) AWSET(14) AWSET(15)
#undef AWSET

    const float bh = bhh[g * 64 + j];

    const float* xrow = xp + (size_t)b * SS * GG;
    float* hrow = hs + (size_t)b * SS * HH;
    float hcur = 0.f;

    float xg = xrow[g * 64 + j];
    float xn = xrow[128 + j];

#define RL(v, k) __int_as_float(__builtin_amdgcn_readlane(__float_as_int(v), (k)))
#define DOT4A(i)                                                               \
    {                                                                          \
        float wx, wy, wz, ww;                                                  \
        asm volatile("v_accvgpr_read_b32 %0, %1" : "=v"(wx) : "a"(aw##i##0));  \
        asm volatile("v_accvgpr_read_b32 %0, %1" : "=v"(wy) : "a"(aw##i##1));  \
        asm volatile("v_accvgpr_read_b32 %0, %1" : "=v"(wz) : "a"(aw##i##2));  \
        asm volatile("v_accvgpr_read_b32 %0, %1" : "=v"(ww) : "a"(aw##i##3));  \
        a0 = fmaf(wx, RL(hcur, 4*(i) + 0), a0);                                \
        a1 = fmaf(wy, RL(hcur, 4*(i) + 1), a1);                                \
        a2 = fmaf(wz, RL(hcur, 4*(i) + 2), a2);                                \
        a3 = fmaf(ww, RL(hcur, 4*(i) + 3), a3);                                \
    }

    for (int s = 0; s < SS; ++s) {
        // Prefetch next step's xp (stays in flight across the lgkm-only
        // barrier; last iter reads past the array into adjacent workspace —
        // harmless, value discarded).
        const float* nx = xrow + GG;
        float nxg = nx[g * 64 + j];
        float nxn = nx[128 + j];

        float a0 = bh, a1 = 0.f, a2 = 0.f, a3 = 0.f;
        DOT4A(0)  DOT4A(1)  DOT4A(2)  DOT4A(3)
        DOT4A(4)  DOT4A(5)  DOT4A(6)  DOT4A(7)
        DOT4A(8)  DOT4A(9)  DOT4A(10) DOT4A(11)
        DOT4A(12) DOT4A(13) DOT4A(14) DOT4A(15)
        float pre = (a0 + a1) + (a2 + a3);
        gh_s[s & 1][t] = (g < 2) ? (xg + pre) : pre;

        // LDS-only barrier: don't drain vmcnt.
        asm volatile("s_waitcnt lgkmcnt(0)" ::: "memory");
        __builtin_amdgcn_s_barrier();
        asm volatile("" ::: "memory");

        float ghr = gh_s[s & 1][j];
        float ghz = gh_s[s & 1][64 + j];
        float ghn = gh_s[s & 1][128 + j];
        float r = sigmoid_f(ghr);
        float z = sigmoid_f(ghz);
        float n = tanh_f(xn + r * ghn);
        hcur = fmaf(z, hcur - n, n);
        if (g == 0) hrow[j] = hcur;

        xg = nxg; xn = nxn;
        xrow += GG;
        hrow += HH;
    }
#undef DOT4A
#undef RL
}

// ---------------------------------------------------------------------------
// FUSED attn_val + scanA. One block per (batch, 16-row tile).
// ---------------------------------------------------------------------------
__global__ __launch_bounds__(128) void attn_scanA_kernel(
    const float* __restrict__ h_alpha, const float* __restrict__ h_beta,
    const float* __restrict__ emb, const float* __restrict__ M,
    const float* __restrict__ Wa, const float* __restrict__ ba,
    const float* __restrict__ Wb, const float* __restrict__ bb,
    float* __restrict__ val, float* __restrict__ wj,
    float* __restrict__ tsum, float* __restrict__ wsum)
{
    const int b = blockIdx.x, tt = blockIdx.y;
    const int t = threadIdx.x;       // 0..127
    const int j0 = tt * 16;
    __shared__ float hb_s[HH];
    __shared__ float wj_s;

    const float bbt = bb[t];
    const float4* wrow = (const float4*)&Wb[(size_t)t * HH];

    float ts = 0.f;
    float ws = 0.f;

    for (int jj = 0; jj < 16; ++jj) {
        const int row = b * SS + j0 + jj;
        if (t < 64) {
            hb_s[t] = h_beta[(size_t)row * HH + t];
            float p = h_alpha[(size_t)row * HH + t] * Wa[t];
            #pragma unroll
            for (int off = 32; off > 0; off >>= 1) p += __shfl_down(p, off);
            if (t == 0) {
                float a = __expf(p + ba[0]) * M[row];
                wj_s = a;
                wj[row] = a;
            }
        }
        __syncthreads();

        float acc = bbt;
        #pragma unroll
        for (int k = 0; k < 16; ++k) {
            float4 w4 = wrow[k];
            float4 h4 = *(const float4*)&hb_s[k * 4];
            acc += w4.x*h4.x + w4.y*h4.y + w4.z*h4.z + w4.w*h4.w;
        }
        float v = tanh_f(acc) * emb[(size_t)row * EE + t] * wj_s;
        val[(size_t)row * EE + t] = v;
        ts += v;
        if (t == 0) ws += wj_s;
        __syncthreads();   // hb_s/wj_s reused next row
    }

    tsum[((size_t)(b * TT + tt)) * EE + t] = ts;
    if (t == 0) wsum[b * TT + tt] = ws;
}

// ---------------------------------------------------------------------------
// FUSED scanB + proj. One block per (batch, 16-row tile); wtd stays in LDS.
// ---------------------------------------------------------------------------
__global__ __launch_bounds__(128) void scanB_proj_kernel(
    const float* __restrict__ val, const float* __restrict__ wj,
    const float* __restrict__ tsum, const float* __restrict__ wsum,
    const float* __restrict__ Wp, const float* __restrict__ bp,
    const float* __restrict__ M, float* __restrict__ out)
{
    const int b = blockIdx.x, tt = blockIdx.y;
    const int t = threadIdx.x;       // 0..127  (= e for the scan phase)
    const int j0 = tt * 16;

    __shared__ float wtd_s[16][132];
    __shared__ float wp_s[8][132];

    // beyond-tile suffix
    float se = 0.f;
    for (int t2 = tt + 1; t2 < TT; ++t2)
        se += tsum[((size_t)(b * TT + t2)) * EE + t];
    float d = 1e-10f;
    for (int t2 = tt + 1; t2 < TT; ++t2)
        d += wsum[b * TT + t2];

    // in-tile suffix (16 steps), results stay in LDS
    for (int jj = 15; jj >= 0; --jj) {
        size_t idx = ((size_t)(b * SS + j0 + jj)) * EE + t;
        se += val[idx];
        d += wj[b * SS + j0 + jj];
        wtd_s[jj][t] = se / d;
    }

    // stage Wp (8 x 128): 256 float4 total, 2 per thread
    #pragma unroll
    for (int it = 0; it < 2; ++it) {
        int idx = t + it * 128;      // 0..255
        int r = idx >> 5;            // 0..7
        int c = idx & 31;            // 0..31
        *(float4*)&wp_s[r][c * 4] = *(const float4*)&Wp[(size_t)r * EE + c * 4];
    }
    __syncthreads();

    // projection: thread = (row r, output l)
    const int r = t >> 3, l = t & 7;
    float acc = 0.f;
    #pragma unroll
    for (int i = 0; i < 32; ++i) {
        float4 a = *(const float4*)&wtd_s[r][i * 4];
        float4 w = *(const float4*)&wp_s[l][i * 4];
        acc += a.x*w.x + a.y*w.y + a.z*w.z + a.w*w.w;
    }
    const int row = b * SS + j0 + r;
    out[(size_t)row * LL + l] = (acc + bp[l]) * M[row];
}

// ---------------------------------------------------------------------------
// cur_output[b,l] = sum_s all_output[b,s,l] * cur_M[b,s]
// ---------------------------------------------------------------------------
__global__ __launch_bounds__(256) void cur_kernel(
    const float* __restrict__ out_all, const float* __restrict__ curM,
    float* __restrict__ out_cur)
{
    const int b = blockIdx.x;
    const int t = threadIdx.x;
    const int l = t & 7, c = t >> 3;
    float p = 0.f;
    #pragma unroll
    for (int k = 0; k < 8; ++k) {
        int s = c + k * 32;
        p += out_all[((size_t)(b * SS + s)) * LL + l] * curM[b * SS + s];
    }
    __shared__ float red[32][9];
    red[c][l] = p;
    __syncthreads();
    if (t < 8) {
        float sum = 0.f;
        for (int c2 = 0; c2 < 32; ++c2) sum += red[c2][t];
        out_cur[b * LL + t] = sum;
    }
}

// ---------------------------------------------------------------------------
extern "C" void kernel_launch(void* const* d_in, const int* in_sizes, int n_in,
                              void* d_out, int out_size, void* d_ws, size_t ws_size,
                              hipStream_t stream)
{
    const float* X       = (const float*)d_in[0];
    const float* M       = (const float*)d_in[1];
    const float* cur_M   = (const float*)d_in[2];
    const float* W_embed = (const float*)d_in[3];
    const float* b_embed = (const float*)d_in[4];
    const float* Wih_a   = (const float*)d_in[5];
    const float* Whh_a   = (const float*)d_in[6];
    const float* bih_a   = (const float*)d_in[7];
    const float* bhh_a   = (const float*)d_in[8];
    const float* Wih_b   = (const float*)d_in[9];
    const float* Whh_b   = (const float*)d_in[10];
    const float* bih_b   = (const float*)d_in[11];
    const float* bhh_b   = (const float*)d_in[12];
    const float* Wb      = (const float*)d_in[13];
    const float* bb      = (const float*)d_in[14];
    const float* Wa      = (const float*)d_in[15];
    const float* ba      = (const float*)d_in[16];
    const float* Wp      = (const float*)d_in[17];
    const float* bp      = (const float*)d_in[18];
    float* out = (float*)d_out;

    float* ws  = (float*)d_ws;
    float* emb = ws;                          // B*S*E
    float* xpa = emb + (size_t)BB*SS*EE;      // B*S*192
    float* xpb = xpa + (size_t)BB*SS*GG;
    float* ha  = xpb + (size_t)BB*SS*GG;      // B*S*H
    float* hb  = ha  + (size_t)BB*SS*HH;
    float* val = hb  + (size_t)BB*SS*HH;      // B*S*E
    float* wjv = val + (size_t)BB*SS*EE;      // B*S
    float* tsum = wjv + (size_t)BB*SS;        // B*TT*E
    float* wsum = tsum + (size_t)BB*TT*EE;    // B*TT

    const int ROWS = BB * SS;                 // 4096

    gemm_bt<<<dim3(ROWS/32, EE/64), 256, 0, stream>>>(X, W_embed, b_embed, emb, EE, FF);
    gemm_bt_dual<<<dim3(ROWS/32, (GG+63)/64, 2), 256, 0, stream>>>(
        emb, Wih_a, bih_a, xpa, Wih_b, bih_b, xpb, GG, EE);
    gru_kernel<<<32, 192, 0, stream>>>(xpa, xpb, Whh_a, bhh_a, Whh_b, bhh_b, ha, hb);
    attn_scanA_kernel<<<dim3(BB, TT), 128, 0, stream>>>(
        ha, hb, emb, M, Wa, ba, Wb, bb, val, wjv, tsum, wsum);
    scanB_proj_kernel<<<dim3(BB, TT), 128, 0, stream>>>(
        val, wjv, tsum, wsum, Wp, bp, M, out);
    cur_kernel<<<BB, 256, 0, stream>>>(out, cur_M, out + (size_t)BB*SS*LL);
}

// Round 16
// 182.918 us; speedup vs baseline: 1.2981x; 1.2981x over previous
//
#include <hip/hip_runtime.h>
#include <math.h>

#define BB 16
#define SS 256
#define FF 512
#define EE 128
#define HH 64
#define GG 192  // 3H
#define LL 8
#define TT 16   // scan tile count (SS/16)

typedef __fp16 f16x2 __attribute__((ext_vector_type(2)));

__device__ __forceinline__ float sigmoid_f(float x) {
    return 1.0f / (1.0f + __expf(-x));
}
__device__ __forceinline__ float tanh_f(float x) {
    return 1.0f - 2.0f / (1.0f + __expf(2.0f * x));
}

// ---------------------------------------------------------------------------
// Generic C[m,n] = sum_k A[m,k] * Bm[n,k] + bias[n]
// ---------------------------------------------------------------------------
__device__ __forceinline__ void gemm_bt_body(
    const float* __restrict__ A, const float* __restrict__ Bm,
    const float* __restrict__ bias, float* __restrict__ C,
    int N, int K)
{
    __shared__ float As[32][68];
    __shared__ float Bs[64][68];
    const int t = threadIdx.x;
    const int row0 = blockIdx.x * 32;
    const int col0 = blockIdx.y * 64;
    const int tr = t & 7;
    const int tc = t >> 3;
    float acc[4][2] = {{0.f,0.f},{0.f,0.f},{0.f,0.f},{0.f,0.f}};

    for (int k0 = 0; k0 < K; k0 += 64) {
        {
            int r = t >> 3;
            int q = t & 7;
            const float* src = &A[(size_t)(row0 + r) * K + k0];
            #pragma unroll
            for (int it = 0; it < 2; ++it) {
                int kk = (q + it * 8) * 4;
                *(float4*)&As[r][kk] = *(const float4*)&src[kk];
            }
        }
        {
            int r = t >> 2;
            int q = t & 3;
            int n = col0 + r;
            #pragma unroll
            for (int it = 0; it < 4; ++it) {
                int kk = (q + it * 4) * 4;
                float4 v = {0.f, 0.f, 0.f, 0.f};
                if (n < N) v = *(const float4*)&Bm[(size_t)n * K + k0 + kk];
                *(float4*)&Bs[r][kk] = v;
            }
        }
        __syncthreads();
        #pragma unroll
        for (int k = 0; k < 64; k += 4) {
            float4 av[4], bv[2];
            #pragma unroll
            for (int i = 0; i < 4; ++i) av[i] = *(const float4*)&As[tr + 8*i][k];
            #pragma unroll
            for (int j = 0; j < 2; ++j) bv[j] = *(const float4*)&Bs[tc + 32*j][k];
            #pragma unroll
            for (int i = 0; i < 4; ++i)
                #pragma unroll
                for (int j = 0; j < 2; ++j)
                    acc[i][j] += av[i].x*bv[j].x + av[i].y*bv[j].y
                               + av[i].z*bv[j].z + av[i].w*bv[j].w;
        }
        __syncthreads();
    }

    #pragma unroll
    for (int i = 0; i < 4; ++i) {
        int r = row0 + tr + 8*i;
        #pragma unroll
        for (int j = 0; j < 2; ++j) {
            int c = col0 + tc + 32*j;
            if (c < N) C[(size_t)r * N + c] = acc[i][j] + bias[c];
        }
    }
}

__global__ __launch_bounds__(256) void gemm_bt(
    const float* __restrict__ A, const float* __restrict__ Bm,
    const float* __restrict__ bias, float* __restrict__ C,
    int N, int K)
{
    gemm_bt_body(A, Bm, bias, C, N, K);
}

__global__ __launch_bounds__(256) void gemm_bt_dual(
    const float* __restrict__ A,
    const float* __restrict__ B0, const float* __restrict__ bias0, float* __restrict__ C0,
    const float* __restrict__ B1, const float* __restrict__ bias1, float* __restrict__ C1,
    int N, int K)
{
    const float* Bm   = blockIdx.z ? B1    : B0;
    const float* bias = blockIdx.z ? bias1 : bias0;
    float*       C    = blockIdx.z ? C1    : C0;
    gemm_bt_body(A, Bm, bias, C, N, K);
}

// ---------------------------------------------------------------------------
// Prep: pack Whh (192x64 fp32) into f16 pairs (192x32 u32), both GRUs.
// ---------------------------------------------------------------------------
__global__ __launch_bounds__(256) void cvt_w16_kernel(
    const float* __restrict__ Whh_a, const float* __restrict__ Whh_b,
    unsigned* __restrict__ wa16, unsigned* __restrict__ wb16)
{
    int i = blockIdx.x * 256 + threadIdx.x;   // 0..6143
    if (i < GG * HH / 2) {
        float2 a = ((const float2*)Whh_a)[i];
        float2 b = ((const float2*)Whh_b)[i];
        f16x2 pa = __builtin_amdgcn_cvt_pkrtz(a.x, a.y);
        f16x2 pb = __builtin_amdgcn_cvt_pkrtz(b.x, b.y);
        wa16[i] = __builtin_bit_cast(unsigned, pa);
        wb16[i] = __builtin_bit_cast(unsigned, pb);
    }
}

// ---------------------------------------------------------------------------
// GRU scan (r16 = r15 + compile fix). SINGLE WAVE per chain: 32 blocks x 64
// threads. Lane j owns h[j] (fp32) and all three gate rows (j, j+64, j+128)
// of Whh as f16 PAIRS (24 named uint4 = 384B/lane, HALF the fp32 bytes).
// Rationale: r2-r14 proved weight residency is unattainable (RA spills or
// remats in every register tier); the measured floor is the per-step weight
// RE-FETCH through one CU's L1 (r10: 48KB/step ~ 750cyc). f16 halves that
// to 24KB, v_dot2_f32_f16 halves the MAC issue count, and the 1-wave layout
// DELETES the barrier and gh LDS exchange. h is quantized to f16 only as
// dot input (cvt_pkrtz pack + 32 shared readlanes); hcur and all gate math
// stay fp32. n = tanh(xn + r*(Wn h + bn)) per torch semantics.
// ---------------------------------------------------------------------------
__global__ __launch_bounds__(64, 1)
__attribute__((amdgpu_waves_per_eu(1, 1)))
void gru_kernel(
    const float* __restrict__ xpa, const float* __restrict__ xpb,
    const unsigned* __restrict__ wa16, const unsigned* __restrict__ wb16,
    const float* __restrict__ bhh_a, const float* __restrict__ bhh_b,
    float* __restrict__ hs_a, float* __restrict__ hs_b)
{
    const int blk = blockIdx.x;      // 0..31
    const int b = blk >> 1;
    const int which = blk & 1;
    const float* xp    = which ? xpb  : xpa;
    const unsigned* wf = which ? wb16 : wa16;
    const float* bhh   = which ? bhh_b : bhh_a;
    float* hs          = which ? hs_b  : hs_a;

    const int j = threadIdx.x;       // 0..63

    const uint4* pr = (const uint4*)(wf + (size_t)j * 32);
    const uint4* pz = (const uint4*)(wf + (size_t)(j + 64) * 32);
    const uint4* pn = (const uint4*)(wf + (size_t)(j + 128) * 32);
    uint4 r0 = pr[0], r1 = pr[1], r2 = pr[2], r3 = pr[3];
    uint4 r4 = pr[4], r5 = pr[5], r6 = pr[6], r7 = pr[7];
    uint4 z0 = pz[0], z1 = pz[1], z2 = pz[2], z3 = pz[3];
    uint4 z4 = pz[4], z5 = pz[5], z6 = pz[6], z7 = pz[7];
    uint4 n0 = pn[0], n1 = pn[1], n2 = pn[2], n3 = pn[3];
    uint4 n4 = pn[4], n5 = pn[5], n6 = pn[6], n7 = pn[7];

    const float br = bhh[j], bz = bhh[j + 64], bn = bhh[j + 128];

    const float* xrow = xp + (size_t)b * SS * GG;
    float* hrow = hs + (size_t)b * SS * HH;
    float hcur = 0.f;

    float xr = xrow[j], xz = xrow[j + 64], xn = xrow[j + 128];

#define BCH(u) __builtin_bit_cast(f16x2, (unsigned)(u))
#define RLH(k) ((unsigned)__builtin_amdgcn_readlane(__builtin_bit_cast(int, hp), (k)))
#define FD(W, H, A) A = __builtin_amdgcn_fdot2(BCH(W), H, A, false)
#define QUAD(q)                                                \
    {                                                          \
        f16x2 h0_ = BCH(RLH(8*(q) + 0));                       \
        f16x2 h1_ = BCH(RLH(8*(q) + 2));                       \
        f16x2 h2_ = BCH(RLH(8*(q) + 4));                       \
        f16x2 h3_ = BCH(RLH(8*(q) + 6));                       \
        FD(r##q.x, h0_, ar0); FD(r##q.y, h1_, ar1);            \
        FD(r##q.z, h2_, ar2); FD(r##q.w, h3_, ar3);            \
        FD(z##q.x, h0_, az0); FD(z##q.y, h1_, az1);            \
        FD(z##q.z, h2_, az2); FD(z##q.w, h3_, az3);            \
        FD(n##q.x, h0_, an0); FD(n##q.y, h1_, an1);            \
        FD(n##q.z, h2_, an2); FD(n##q.w, h3_, an3);            \
    }

    for (int s = 0; s < SS; ++s) {
        // Prefetch next step's xp (last iter over-reads into the adjacent
        // workspace region — harmless, value discarded).
        const float* nx = xrow + GG;
        float nxr = nx[j], nxz = nx[j + 64], nxn = nx[128 + j];

        // pack (h[2k], h[2k+1]) into every lane of the pair
        float partner = __shfl_xor(hcur, 1);
        float ev = (j & 1) ? partner : hcur;
        float od = (j & 1) ? hcur : partner;
        f16x2 hp = __builtin_amdgcn_cvt_pkrtz(ev, od);

        float ar0 = br, ar1 = 0.f, ar2 = 0.f, ar3 = 0.f;
        float az0 = bz, az1 = 0.f, az2 = 0.f, az3 = 0.f;
        float an0 = bn, an1 = 0.f, an2 = 0.f, an3 = 0.f;
        QUAD(0) QUAD(1) QUAD(2) QUAD(3)
        QUAD(4) QUAD(5) QUAD(6) QUAD(7)
        float arr = (ar0 + ar1) + (ar2 + ar3);
        float azz = (az0 + az1) + (az2 + az3);
        float ann = (an0 + an1) + (an2 + an3);

        float r = sigmoid_f(xr + arr);
        float z = sigmoid_f(xz + azz);
        float n = tanh_f(xn + r * ann);
        hcur = fmaf(z, hcur - n, n);
        hrow[j] = hcur;

        xr = nxr; xz = nxz; xn = nxn;
        xrow += GG;
        hrow += HH;
    }
#undef QUAD
#undef FD
#undef RLH
#undef BCH
}

// ---------------------------------------------------------------------------
// FUSED attn_val + scanA. One block per (batch, 16-row tile).
// ---------------------------------------------------------------------------
__global__ __launch_bounds__(128) void attn_scanA_kernel(
    const float* __restrict__ h_alpha, const float* __restrict__ h_beta,
    const float* __restrict__ emb, const float* __restrict__ M,
    const float* __restrict__ Wa, const float* __restrict__ ba,
    const float* __restrict__ Wb, const float* __restrict__ bb,
    float* __restrict__ val, float* __restrict__ wj,
    float* __restrict__ tsum, float* __restrict__ wsum)
{
    const int b = blockIdx.x, tt = blockIdx.y;
    const int t = threadIdx.x;       // 0..127
    const int j0 = tt * 16;
    __shared__ float hb_s[HH];
    __shared__ float wj_s;

    const float bbt = bb[t];
    const float4* wrow = (const float4*)&Wb[(size_t)t * HH];

    float ts = 0.f;
    float ws = 0.f;

    for (int jj = 0; jj < 16; ++jj) {
        const int row = b * SS + j0 + jj;
        if (t < 64) {
            hb_s[t] = h_beta[(size_t)row * HH + t];
            float p = h_alpha[(size_t)row * HH + t] * Wa[t];
            #pragma unroll
            for (int off = 32; off > 0; off >>= 1) p += __shfl_down(p, off);
            if (t == 0) {
                float a = __expf(p + ba[0]) * M[row];
                wj_s = a;
                wj[row] = a;
            }
        }
        __syncthreads();

        float acc = bbt;
        #pragma unroll
        for (int k = 0; k < 16; ++k) {
            float4 w4 = wrow[k];
            float4 h4 = *(const float4*)&hb_s[k * 4];
            acc += w4.x*h4.x + w4.y*h4.y + w4.z*h4.z + w4.w*h4.w;
        }
        float v = tanh_f(acc) * emb[(size_t)row * EE + t] * wj_s;
        val[(size_t)row * EE + t] = v;
        ts += v;
        if (t == 0) ws += wj_s;
        __syncthreads();   // hb_s/wj_s reused next row
    }

    tsum[((size_t)(b * TT + tt)) * EE + t] = ts;
    if (t == 0) wsum[b * TT + tt] = ws;
}

// ---------------------------------------------------------------------------
// FUSED scanB + proj. One block per (batch, 16-row tile); wtd stays in LDS.
// ---------------------------------------------------------------------------
__global__ __launch_bounds__(128) void scanB_proj_kernel(
    const float* __restrict__ val, const float* __restrict__ wj,
    const float* __restrict__ tsum, const float* __restrict__ wsum,
    const float* __restrict__ Wp, const float* __restrict__ bp,
    const float* __restrict__ M, float* __restrict__ out)
{
    const int b = blockIdx.x, tt = blockIdx.y;
    const int t = threadIdx.x;       // 0..127  (= e for the scan phase)
    const int j0 = tt * 16;

    __shared__ float wtd_s[16][132];
    __shared__ float wp_s[8][132];

    // beyond-tile suffix
    float se = 0.f;
    for (int t2 = tt + 1; t2 < TT; ++t2)
        se += tsum[((size_t)(b * TT + t2)) * EE + t];
    float d = 1e-10f;
    for (int t2 = tt + 1; t2 < TT; ++t2)
        d += wsum[b * TT + t2];

    // in-tile suffix (16 steps), results stay in LDS
    for (int jj = 15; jj >= 0; --jj) {
        size_t idx = ((size_t)(b * SS + j0 + jj)) * EE + t;
        se += val[idx];
        d += wj[b * SS + j0 + jj];
        wtd_s[jj][t] = se / d;
    }

    // stage Wp (8 x 128): 256 float4 total, 2 per thread
    #pragma unroll
    for (int it = 0; it < 2; ++it) {
        int idx = t + it * 128;      // 0..255
        int r = idx >> 5;            // 0..7
        int c = idx & 31;            // 0..31
        *(float4*)&wp_s[r][c * 4] = *(const float4*)&Wp[(size_t)r * EE + c * 4];
    }
    __syncthreads();

    // projection: thread = (row r, output l)
    const int r = t >> 3, l = t & 7;
    float acc = 0.f;
    #pragma unroll
    for (int i = 0; i < 32; ++i) {
        float4 a = *(const float4*)&wtd_s[r][i * 4];
        float4 w = *(const float4*)&wp_s[l][i * 4];
        acc += a.x*w.x + a.y*w.y + a.z*w.z + a.w*w.w;
    }
    const int row = b * SS + j0 + r;
    out[(size_t)row * LL + l] = (acc + bp[l]) * M[row];
}

// ---------------------------------------------------------------------------
// cur_output[b,l] = sum_s all_output[b,s,l] * cur_M[b,s]
// ---------------------------------------------------------------------------
__global__ __launch_bounds__(256) void cur_kernel(
    const float* __restrict__ out_all, const float* __restrict__ curM,
    float* __restrict__ out_cur)
{
    const int b = blockIdx.x;
    const int t = threadIdx.x;
    const int l = t & 7, c = t >> 3;
    float p = 0.f;
    #pragma unroll
    for (int k = 0; k < 8; ++k) {
        int s = c + k * 32;
        p += out_all[((size_t)(b * SS + s)) * LL + l] * curM[b * SS + s];
    }
    __shared__ float red[32][9];
    red[c][l] = p;
    __syncthreads();
    if (t < 8) {
        float sum = 0.f;
        for (int c2 = 0; c2 < 32; ++c2) sum += red[c2][t];
        out_cur[b * LL + t] = sum;
    }
}

// ---------------------------------------------------------------------------
extern "C" void kernel_launch(void* const* d_in, const int* in_sizes, int n_in,
                              void* d_out, int out_size, void* d_ws, size_t ws_size,
                              hipStream_t stream)
{
    const float* X       = (const float*)d_in[0];
    const float* M       = (const float*)d_in[1];
    const float* cur_M   = (const float*)d_in[2];
    const float* W_embed = (const float*)d_in[3];
    const float* b_embed = (const float*)d_in[4];
    const float* Wih_a   = (const float*)d_in[5];
    const float* Whh_a   = (const float*)d_in[6];
    const float* bih_a   = (const float*)d_in[7];
    const float* bhh_a   = (const float*)d_in[8];
    const float* Wih_b   = (const float*)d_in[9];
    const float* Whh_b   = (const float*)d_in[10];
    const float* bih_b   = (const float*)d_in[11];
    const float* bhh_b   = (const float*)d_in[12];
    const float* Wb      = (const float*)d_in[13];
    const float* bb      = (const float*)d_in[14];
    const float* Wa      = (const float*)d_in[15];
    const float* ba      = (const float*)d_in[16];
    const float* Wp      = (const float*)d_in[17];
    const float* bp      = (const float*)d_in[18];
    float* out = (float*)d_out;

    float* ws  = (float*)d_ws;
    float* emb = ws;                          // B*S*E
    float* xpa = emb + (size_t)BB*SS*EE;      // B*S*192
    float* xpb = xpa + (size_t)BB*SS*GG;
    float* ha  = xpb + (size_t)BB*SS*GG;      // B*S*H
    float* hb  = ha  + (size_t)BB*SS*HH;
    float* val = hb  + (size_t)BB*SS*HH;      // B*S*E
    float* wjv = val + (size_t)BB*SS*EE;      // B*S
    float* tsum = wjv + (size_t)BB*SS;        // B*TT*E
    float* wsum = tsum + (size_t)BB*TT*EE;    // B*TT
    unsigned* wa16 = (unsigned*)(wsum + (size_t)BB*TT);  // 6144 u32
    unsigned* wb16 = wa16 + (size_t)GG*HH/2;             // 6144 u32

    const int ROWS = BB * SS;                 // 4096

    cvt_w16_kernel<<<24, 256, 0, stream>>>(Whh_a, Whh_b, wa16, wb16);
    gemm_bt<<<dim3(ROWS/32, EE/64), 256, 0, stream>>>(X, W_embed, b_embed, emb, EE, FF);
    gemm_bt_dual<<<dim3(ROWS/32, (GG+63)/64, 2), 256, 0, stream>>>(
        emb, Wih_a, bih_a, xpa, Wih_b, bih_b, xpb, GG, EE);
    gru_kernel<<<32, 64, 0, stream>>>(xpa, xpb, wa16, wb16, bhh_a, bhh_b, ha, hb);
    attn_scanA_kernel<<<dim3(BB, TT), 128, 0, stream>>>(
        ha, hb, emb, M, Wa, ba, Wb, bb, val, wjv, tsum, wsum);
    scanB_proj_kernel<<<dim3(BB, TT), 128, 0, stream>>>(
        val, wjv, tsum, wsum, Wp, bp, M, out);
    cur_kernel<<<BB, 256, 0, stream>>>(out, cur_M, out + (size_t)BB*SS*LL);
}